// Round 11
// baseline (566.010 us; speedup 1.0000x reference)
//
#include <hip/hip_runtime.h>
#include <hip/hip_bf16.h>

// Bucket-scatter + bucket-local sort + per-node reduce:
//   S = hidden @ Ws.T, R = rela @ Wr.T, Q[b] = rela[q_rel[b]] @ Wqr.T + bqr
//   hist_pack: bucket counts (obj>>6, line-padded) + pk2[e]={sub|rel<<17, obj|ridx<<20}
//   bscan: exclusive scan of 1563 bucket counts (1 block); offs[n_node] = total
//   alpha_scatter: rec_b[bcur[bucket]++] = {alpha, sub|rel<<17|objlow<<26}
//       (frontier = 1563 lines -> fits per-XCD L2 -> write-combining works; R8 evidence)
//   bucket_sort: per bucket, LDS count/scan over 64 node slots -> per-node offs,
//       re-stream records into per-node sorted order (dense writes in bucket range)
//   reduce: one wave per node, 4 records in flight, float4 gathers -> d_out (agg)
//   outgemm_inplace: d_out rows <- d_out rows @ Wh.T

#define BSH 6
#define BNODES (1 << BSH)
#define CPAD 16              // 64B line per bucket counter

__global__ void proj32_kernel(const float* __restrict__ X, const float* __restrict__ W,
                              float* __restrict__ out, int nrows) {
    // out[n][k] = sum_d X[n][d] * W[k][d],  k<32, d<64
    __shared__ float wT[64 * 32];
    int tid = threadIdx.x;
    for (int i = tid; i < 32 * 64; i += 256) {
        int k = i >> 6, d = i & 63;
        wT[d * 32 + k] = W[i];
    }
    __syncthreads();
    int row = blockIdx.x * 8 + (tid >> 5);
    int k = tid & 31;
    if (row >= nrows) return;
    const float4* X4 = (const float4*)(X + (size_t)row * 64);
    float acc = 0.f;
#pragma unroll
    for (int d4 = 0; d4 < 16; ++d4) {
        float4 x = X4[d4];
        int d = d4 * 4;
        acc += x.x * wT[(d + 0) * 32 + k] + x.y * wT[(d + 1) * 32 + k]
             + x.z * wT[(d + 2) * 32 + k] + x.w * wT[(d + 3) * 32 + k];
    }
    out[(size_t)row * 32 + k] = acc;
}

__global__ void qproj_kernel(const int* __restrict__ q_rel, const float* __restrict__ rela,
                             const float* __restrict__ Wqr, const float* __restrict__ bqr,
                             float* __restrict__ Q, int batch) {
    int tid = threadIdx.x;
    int b = tid >> 5, k = tid & 31;
    if (b >= batch) return;
    int qr = q_rel[b];
    const float* x = rela + (size_t)qr * 64;
    const float* w = Wqr + (size_t)k * 64;
    float acc = bqr[k];
    for (int d = 0; d < 64; ++d) acc += w[d] * x[d];
    Q[b * 32 + k] = acc;
}

// one thread per edge: bucket histogram + packed edge headers.
// pk2.x = sub | rel<<17  (sub<2^17, rel<2^9)
// pk2.y = obj | ridx<<20 (obj<2^17, ridx<8)
__global__ void hist_pack_kernel(const int* __restrict__ edges, int* __restrict__ bcounts,
                                 int2* __restrict__ pk2, int n_edge) {
    int e = blockIdx.x * 256 + threadIdx.x;
    if (e >= n_edge) return;
    const int* ep = edges + (size_t)e * 6;
    int2 a01 = *(const int2*)ep;        // {r_idx, pad}
    int2 a23 = *(const int2*)(ep + 2);  // {rel, pad}
    int2 a45 = *(const int2*)(ep + 4);  // {sub, obj}
    atomicAdd(&bcounts[(a45.y >> BSH) * CPAD], 1);
    pk2[e] = make_int2(a45.x | (a23.x << 17), a45.y | (a01.x << 20));
}

// single block: exclusive scan over NB bucket counts -> boffs (dense), bcur (padded);
// thread 0 finally writes offs[n_node] = grand total.
__global__ void bscan_kernel(const int* __restrict__ bcounts, int* __restrict__ boffs,
                             int* __restrict__ bcur, int* __restrict__ offs,
                             int NB, int n_node) {
    __shared__ int s[256];
    __shared__ int carry_s;
    int tid = threadIdx.x;
    if (tid == 0) carry_s = 0;
    __syncthreads();
    for (int base = 0; base < NB; base += 256) {
        int idx = base + tid;
        int v = (idx < NB) ? bcounts[idx * CPAD] : 0;
        s[tid] = v;
        __syncthreads();
        for (int off = 1; off < 256; off <<= 1) {
            int t = (tid >= off) ? s[tid - off] : 0;
            __syncthreads();
            s[tid] += t;
            __syncthreads();
        }
        int excl = carry_s + s[tid] - v;
        if (idx < NB) { boffs[idx] = excl; bcur[idx * CPAD] = excl; }
        __syncthreads();
        if (tid == 0) carry_s += s[255];
        __syncthreads();
    }
    if (tid == 0) { boffs[NB] = carry_s; offs[n_node] = carry_s; }
}

// 16 lanes per edge: packed header load, gather S/R/Q, alpha, bucket scatter.
__global__ void alpha_scatter_kernel(const int2* __restrict__ pk2,
                                     const float2* __restrict__ S2,
                                     const float2* __restrict__ R2,
                                     const float2* __restrict__ Q2,
                                     const float2* __restrict__ w2,
                                     const float* __restrict__ w_alpha_b,
                                     int* __restrict__ bcur, float2* __restrict__ rec_b,
                                     int n_edge) {
    int tid = threadIdx.x;
    int lane = tid & 15;
    int e = blockIdx.x * 16 + (tid >> 4);
    if (e >= n_edge) return;
    int2 h = pk2[e];                 // broadcast across the 16-lane group
    int sub  = h.x & 0x1FFFF;
    int rel  = h.x >> 17;            // upper bits of h.x are zero here
    int obj  = h.y & 0x1FFFF;
    int ridx = h.y >> 20;
    float2 s = S2[(size_t)sub * 16 + lane];
    float2 r = R2[(size_t)rel * 16 + lane];
    float2 q = Q2[ridx * 16 + lane];
    float a0 = fmaxf(s.x + r.x + q.x, 0.f);
    float a1 = fmaxf(s.y + r.y + q.y, 0.f);
    float2 w = w2[lane];
    float p = a0 * w.x + a1 * w.y;
#pragma unroll
    for (int off = 8; off > 0; off >>= 1) p += __shfl_xor(p, off, 16);
    if (lane == 0) {
        float alpha = 1.f / (1.f + __expf(-(p + w_alpha_b[0])));
        int pos = atomicAdd(&bcur[(obj >> BSH) * CPAD], 1);
        float2 out;
        out.x = alpha;
        out.y = __int_as_float(h.x | ((obj & (BNODES - 1)) << 26)); // sub|rel<<17|objlow<<26
        rec_b[pos] = out;
    }
}

// one block per bucket: per-node counts in LDS, scan -> offs, re-stream into sorted order.
__global__ void bucket_sort_kernel(const float2* __restrict__ rec_b,
                                   const int* __restrict__ boffs,
                                   int* __restrict__ offs, float2* __restrict__ rec_s,
                                   int n_node) {
    __shared__ int cnt[BNODES];
    __shared__ int pos[BNODES];
    int tid = threadIdx.x;
    int b = blockIdx.x;
    if (tid < BNODES) cnt[tid] = 0;
    __syncthreads();
    int start = boffs[b], end = boffs[b + 1];
    for (int i = start + tid; i < end; i += 256) {
        int pk = __float_as_int(rec_b[i].y);
        atomicAdd(&cnt[((unsigned)pk) >> 26], 1);
    }
    __syncthreads();
    if (tid < BNODES) {
        int p = 0;
        for (int k = 0; k < tid; ++k) p += cnt[k];   // 64-wide naive prefix, trivial cost
        pos[tid] = p;
        int node = (b << BSH) + tid;
        if (node < n_node) offs[node] = start + p;
    }
    __syncthreads();
    if (tid < BNODES) cnt[tid] = pos[tid];           // reuse as cursors
    __syncthreads();
    for (int i = start + tid; i < end; i += 256) {
        float2 r = rec_b[i];
        int nl = ((unsigned)__float_as_int(r.y)) >> 26;
        int lp = atomicAdd(&cnt[nl], 1);
        rec_s[start + lp] = r;                       // dense writes within bucket range
    }
}

// one 64-lane wave per node; 4 records in flight (groups of 16 lanes, float4 loads)
__global__ void reduce_kernel(const float2* __restrict__ rec, const int* __restrict__ offs,
                              const float4* __restrict__ hidden4,
                              const float4* __restrict__ rela4,
                              float4* __restrict__ out4, int n_node) {
    int lane = threadIdx.x & 63;
    int node = blockIdx.x * 4 + (threadIdx.x >> 6);
    if (node >= n_node) return;
    int g = lane >> 4;        // record subgroup 0..3
    int t = lane & 15;        // dim-quad index 0..15
    int start = offs[node], end = offs[node + 1];
    float4 acc = make_float4(0.f, 0.f, 0.f, 0.f);
    for (int i = start; i < end; i += 64) {
        int m = end - i;
        if (m > 64) m = 64;
        float a = 0.f;        // a=0 for idle lanes -> tail records contribute 0
        int pk = 0;
        if (lane < m) {
            float2 r = rec[i + lane];
            a = r.x;
            pk = __float_as_int(r.y);
        }
        for (int j = 0; 4 * j < m; ++j) {
            int src = 4 * j + g;
            float aj = __shfl(a, src, 64);
            int pkj = __shfl(pk, src, 64);
            int sub = pkj & 0x1FFFF, rel = (pkj >> 17) & 0x1FF;  // mask: bits 26+ = objlow
            float4 h = hidden4[(size_t)sub * 16 + t];
            float4 rr = rela4[(size_t)rel * 16 + t];
            acc.x += aj * (h.x + rr.x);
            acc.y += aj * (h.y + rr.y);
            acc.z += aj * (h.z + rr.z);
            acc.w += aj * (h.w + rr.w);
        }
    }
#pragma unroll
    for (int off = 16; off <= 32; off <<= 1) {
        acc.x += __shfl_xor(acc.x, off, 64);
        acc.y += __shfl_xor(acc.y, off, 64);
        acc.z += __shfl_xor(acc.z, off, 64);
        acc.w += __shfl_xor(acc.w, off, 64);
    }
    if (g == 0) out4[(size_t)node * 16 + t] = acc;
}

// in-place: io rows <- io rows @ Wh.T; rows streamed via wave-uniform float4 loads
__global__ void outgemm_inplace_kernel(const float* __restrict__ Wh, float* __restrict__ io,
                                       int n_node) {
    __shared__ float wT[64 * 64];   // wT[d*64+j] = Wh[j*64+d]
    int tid = threadIdx.x;
    for (int i = tid; i < 64 * 64; i += 256) {
        int j = i >> 6, d = i & 63;
        wT[d * 64 + j] = Wh[i];
    }
    __syncthreads();
    int wave = tid >> 6, j = tid & 63;
    int base = blockIdx.x * 32;              // 32 rows per block, 8 per wave
    for (int r = wave; r < 32; r += 4) {
        int row = base + r;
        if (row >= n_node) break;
        const float4* rp = (const float4*)(io + (size_t)row * 64);
        float acc = 0.f;
#pragma unroll
        for (int d4 = 0; d4 < 16; ++d4) {
            float4 m4 = rp[d4];              // wave-uniform broadcast load (L1)
            int d = d4 * 4;
            acc += m4.x * wT[(d + 0) * 64 + j] + m4.y * wT[(d + 1) * 64 + j]
                 + m4.z * wT[(d + 2) * 64 + j] + m4.w * wT[(d + 3) * 64 + j];
        }
        io[(size_t)row * 64 + j] = acc;      // same wave read the row fully first
    }
}

extern "C" void kernel_launch(void* const* d_in, const int* in_sizes, int n_in,
                              void* d_out, int out_size, void* d_ws, size_t ws_size,
                              hipStream_t stream) {
    const int*   q_rel     = (const int*)d_in[1];
    const float* hidden    = (const float*)d_in[2];
    const int*   edges     = (const int*)d_in[3];
    const float* rela      = (const float*)d_in[7];
    const float* Ws        = (const float*)d_in[8];
    const float* Wr        = (const float*)d_in[9];
    const float* Wqr       = (const float*)d_in[10];
    const float* bqr       = (const float*)d_in[11];
    const float* w_alpha_w = (const float*)d_in[12];
    const float* w_alpha_b = (const float*)d_in[13];
    const float* Wh        = (const float*)d_in[14];

    int n_node = in_sizes[2] / 64;
    int n_edge = in_sizes[3] / 6;
    int n_rel  = in_sizes[7] / 64;
    int batch  = in_sizes[1];

    int nbuck = (n_node + BNODES - 1) >> BSH;

    // workspace layout (~46 MB); pk2 buffer is reused as rec_s after alpha_scatter
    float* S      = (float*)d_ws;                         // n_node*32
    float* R      = S + (size_t)n_node * 32;              // n_rel*32
    float* Q      = R + (size_t)n_rel * 32;               // batch*32
    int* bcounts  = (int*)(Q + (size_t)batch * 32);       // nbuck*CPAD
    int* boffs    = bcounts + (size_t)nbuck * CPAD;       // nbuck+1
    int* bcur     = boffs + nbuck + 1;                    // nbuck*CPAD
    int* offs     = bcur + (size_t)nbuck * CPAD;          // n_node+1
    size_t rb_off = (size_t)(offs + n_node + 1 - (int*)d_ws);
    rb_off = (rb_off + 3) & ~(size_t)3;                   // align 16B
    float2* rec_b = (float2*)((int*)d_ws + rb_off);       // n_edge float2
    int2*  pk2    = (int2*)(rec_b + n_edge);              // n_edge int2 (later rec_s)
    float2* rec_s = (float2*)pk2;

    (void)hipMemsetAsync(bcounts, 0, (size_t)nbuck * CPAD * sizeof(int), stream);

    proj32_kernel<<<(n_node + 7) / 8, 256, 0, stream>>>(hidden, Ws, S, n_node);
    proj32_kernel<<<(n_rel + 7) / 8, 256, 0, stream>>>(rela, Wr, R, n_rel);
    qproj_kernel<<<1, 256, 0, stream>>>(q_rel, rela, Wqr, bqr, Q, batch);

    hist_pack_kernel<<<(n_edge + 255) / 256, 256, 0, stream>>>(edges, bcounts, pk2, n_edge);
    bscan_kernel<<<1, 256, 0, stream>>>(bcounts, boffs, bcur, offs, nbuck, n_node);

    alpha_scatter_kernel<<<(n_edge + 15) / 16, 256, 0, stream>>>(
        pk2, (const float2*)S, (const float2*)R, (const float2*)Q,
        (const float2*)w_alpha_w, w_alpha_b, bcur, rec_b, n_edge);

    bucket_sort_kernel<<<nbuck, 256, 0, stream>>>(rec_b, boffs, offs, rec_s, n_node);

    reduce_kernel<<<(n_node + 3) / 4, 256, 0, stream>>>(
        rec_s, offs, (const float4*)hidden, (const float4*)rela, (float4*)d_out, n_node);
    outgemm_inplace_kernel<<<(n_node + 31) / 32, 256, 0, stream>>>(Wh, (float*)d_out, n_node);
}

// Round 12
// 529.704 us; speedup vs baseline: 1.0685x; 1.0685x over previous
//
#include <hip/hip_runtime.h>
#include <hip/hip_bf16.h>

// R10 structure (per-node counting sort) + bf16 gather tables:
//   Sb = bf16(hidden @ Ws.T), Rb = bf16(rela @ Wr.T), Qb = bf16(q proj)   [packed 2/uint]
//   hist+pack: counts[obj]++; pk2[e] = {sub|rel<<17, obj|ridx<<20}
//   multi-block exclusive scan -> offs/cur
//   alpha+scatter: alpha = sigmoid(...); rec[cur[obj]++] = {alpha, sub|rel<<17}
//   Hb = bf16(hidden), Rlb = bf16(rela)   [converted after scatter, overlaying pk2]
//   reduce: one wave per node, 4 records in flight, bf16x4 gathers -> d_out (agg f32)
//   outgemm_inplace: d_out rows <- d_out rows @ Wh.T

__device__ inline unsigned short f2bf(float x) {
    unsigned u = __float_as_uint(x);
    u += 0x7FFF + ((u >> 16) & 1);          // round-to-nearest-even
    return (unsigned short)(u >> 16);
}
__device__ inline float bf2f(unsigned short b) {
    return __uint_as_float(((unsigned)b) << 16);
}

// out[n][k] = sum_d X[n][d]*W[k][d], k<32, d<64; emitted as bf16 pairs (uint)
__global__ void proj32_bf16_kernel(const float* __restrict__ X, const float* __restrict__ W,
                                   unsigned* __restrict__ out, int nrows) {
    __shared__ float wT[64 * 32];
    int tid = threadIdx.x;
    for (int i = tid; i < 32 * 64; i += 256) {
        int k = i >> 6, d = i & 63;
        wT[d * 32 + k] = W[i];
    }
    __syncthreads();
    int row = blockIdx.x * 8 + (tid >> 5);
    int k = tid & 31;
    if (row >= nrows) return;
    const float4* X4 = (const float4*)(X + (size_t)row * 64);
    float acc = 0.f;
#pragma unroll
    for (int d4 = 0; d4 < 16; ++d4) {
        float4 x = X4[d4];
        int d = d4 * 4;
        acc += x.x * wT[(d + 0) * 32 + k] + x.y * wT[(d + 1) * 32 + k]
             + x.z * wT[(d + 2) * 32 + k] + x.w * wT[(d + 3) * 32 + k];
    }
    float other = __shfl_xor(acc, 1, 64);   // pair partner (k^1)
    if ((k & 1) == 0) {
        unsigned lo = f2bf(acc), hi = f2bf(other);
        out[(size_t)row * 16 + (k >> 1)] = lo | (hi << 16);
    }
}

__global__ void qproj_bf16_kernel(const int* __restrict__ q_rel, const float* __restrict__ rela,
                                  const float* __restrict__ Wqr, const float* __restrict__ bqr,
                                  unsigned* __restrict__ Qb, int batch) {
    int tid = threadIdx.x;
    int b = tid >> 5, k = tid & 31;
    if (b >= batch) return;
    int qr = q_rel[b];
    const float* x = rela + (size_t)qr * 64;
    const float* w = Wqr + (size_t)k * 64;
    float acc = bqr[k];
    for (int d = 0; d < 64; ++d) acc += w[d] * x[d];
    float other = __shfl_xor(acc, 1, 64);
    if ((k & 1) == 0) {
        unsigned lo = f2bf(acc), hi = f2bf(other);
        Qb[b * 16 + (k >> 1)] = lo | (hi << 16);
    }
}

// f32 -> bf16 table conversion (4 elems/thread)
__global__ void tobf16_kernel(const float4* __restrict__ in, ushort4* __restrict__ out, int n4) {
    int i = blockIdx.x * 256 + threadIdx.x;
    if (i >= n4) return;
    float4 v = in[i];
    ushort4 o;
    o.x = f2bf(v.x); o.y = f2bf(v.y); o.z = f2bf(v.z); o.w = f2bf(v.w);
    out[i] = o;
}

// one thread per edge: histogram of obj AND pack edge fields into dense 8B records.
__global__ void hist_pack_kernel(const int* __restrict__ edges, int* __restrict__ counts,
                                 int2* __restrict__ pk2, int n_edge) {
    int e = blockIdx.x * 256 + threadIdx.x;
    if (e >= n_edge) return;
    const int* ep = edges + (size_t)e * 6;
    int2 a01 = *(const int2*)ep;        // {r_idx, pad}
    int2 a23 = *(const int2*)(ep + 2);  // {rel, pad}
    int2 a45 = *(const int2*)(ep + 4);  // {sub, obj}
    atomicAdd(&counts[a45.y], 1);
    pk2[e] = make_int2(a45.x | (a23.x << 17), a45.y | (a01.x << 20));
}

// ---- multi-block exclusive scan (counts[0..N) -> offs[0..N], cur[0..N)) ----
#define SCAN_CHUNK 1024

__global__ void scan_partial_kernel(const int* __restrict__ counts, int* __restrict__ bsum,
                                    int N) {
    __shared__ int s[256];
    int base = blockIdx.x * SCAN_CHUNK;
    int tid = threadIdx.x;
    int sum = 0;
#pragma unroll
    for (int k = 0; k < 4; ++k) {
        int idx = base + k * 256 + tid;
        if (idx < N) sum += counts[idx];
    }
    s[tid] = sum;
    __syncthreads();
    for (int off = 128; off > 0; off >>= 1) {
        if (tid < off) s[tid] += s[tid + off];
        __syncthreads();
    }
    if (tid == 0) bsum[blockIdx.x] = s[0];
}

__global__ void scan_bsum_kernel(int* __restrict__ bsum, int* __restrict__ offs, int B, int N) {
    __shared__ int s[1024];
    int tid = threadIdx.x;
    int v = (tid < B) ? bsum[tid] : 0;
    s[tid] = v;
    __syncthreads();
    for (int off = 1; off < 1024; off <<= 1) {
        int t = (tid >= off) ? s[tid - off] : 0;
        __syncthreads();
        s[tid] += t;
        __syncthreads();
    }
    if (tid < B) bsum[tid] = s[tid] - v;   // exclusive block prefix
    if (tid == 0) offs[N] = s[1023];       // grand total
}

__global__ void scan_final_kernel(const int* __restrict__ counts, const int* __restrict__ bsum,
                                  int* __restrict__ offs, int* __restrict__ cur, int N) {
    __shared__ int s[256];
    int base = blockIdx.x * SCAN_CHUNK;
    int tid = threadIdx.x;
    int v[4];
    int sum = 0;
#pragma unroll
    for (int k = 0; k < 4; ++k) {
        int idx = base + tid * 4 + k;
        v[k] = (idx < N) ? counts[idx] : 0;
        sum += v[k];
    }
    s[tid] = sum;
    __syncthreads();
    for (int off = 1; off < 256; off <<= 1) {
        int t = (tid >= off) ? s[tid - off] : 0;
        __syncthreads();
        s[tid] += t;
        __syncthreads();
    }
    int run = bsum[blockIdx.x] + s[tid] - sum;
#pragma unroll
    for (int k = 0; k < 4; ++k) {
        int idx = base + tid * 4 + k;
        if (idx < N) { offs[idx] = run; cur[idx] = run; }
        run += v[k];
    }
}

// 16 lanes per edge: packed header, bf16 gathers, alpha, per-node scatter.
__global__ void alpha_scatter_kernel(const int2* __restrict__ pk2,
                                     const unsigned* __restrict__ Sb,
                                     const unsigned* __restrict__ Rb,
                                     const unsigned* __restrict__ Qb,
                                     const float2* __restrict__ w2,
                                     const float* __restrict__ w_alpha_b,
                                     int* __restrict__ cur, float2* __restrict__ rec,
                                     int n_edge) {
    int tid = threadIdx.x;
    int lane = tid & 15;
    int e = blockIdx.x * 16 + (tid >> 4);
    if (e >= n_edge) return;
    int2 h = pk2[e];                 // broadcast across the 16-lane group
    int sub  = h.x & 0x1FFFF;
    int rel  = h.x >> 17;
    int obj  = h.y & 0x1FFFF;
    int ridx = h.y >> 20;
    unsigned sv = Sb[(size_t)sub * 16 + lane];
    unsigned rv = Rb[(size_t)rel * 16 + lane];
    unsigned qv = Qb[ridx * 16 + lane];
    float a0 = fmaxf(bf2f((unsigned short)sv) + bf2f((unsigned short)rv)
                     + bf2f((unsigned short)qv), 0.f);
    float a1 = fmaxf(bf2f((unsigned short)(sv >> 16)) + bf2f((unsigned short)(rv >> 16))
                     + bf2f((unsigned short)(qv >> 16)), 0.f);
    float2 w = w2[lane];
    float p = a0 * w.x + a1 * w.y;
#pragma unroll
    for (int off = 8; off > 0; off >>= 1) p += __shfl_xor(p, off, 16);
    if (lane == 0) {
        float alpha = 1.f / (1.f + __expf(-(p + w_alpha_b[0])));
        int pos = atomicAdd(&cur[obj], 1);
        float2 out;
        out.x = alpha;
        out.y = __int_as_float(h.x);            // sub | rel<<17
        rec[pos] = out;
    }
}

// one 64-lane wave per node; 4 records in flight; bf16x4 gathers, f32 accumulate
__global__ void reduce_kernel(const float2* __restrict__ rec, const int* __restrict__ offs,
                              const ushort4* __restrict__ Hb4,
                              const ushort4* __restrict__ Rb4,
                              float4* __restrict__ out4, int n_node) {
    int lane = threadIdx.x & 63;
    int node = blockIdx.x * 4 + (threadIdx.x >> 6);
    if (node >= n_node) return;
    int g = lane >> 4;        // record subgroup 0..3
    int t = lane & 15;        // dim-quad index 0..15
    int start = offs[node], end = offs[node + 1];
    float4 acc = make_float4(0.f, 0.f, 0.f, 0.f);
    for (int i = start; i < end; i += 64) {
        int m = end - i;
        if (m > 64) m = 64;
        float a = 0.f;        // a=0 for idle lanes -> tail records contribute 0
        int pk = 0;
        if (lane < m) {
            float2 r = rec[i + lane];
            a = r.x;
            pk = __float_as_int(r.y);
        }
        for (int j = 0; 4 * j < m; ++j) {
            int src = 4 * j + g;
            float aj = __shfl(a, src, 64);
            int pkj = __shfl(pk, src, 64);
            int sub = pkj & 0x1FFFF, rel = pkj >> 17;
            ushort4 hu = Hb4[(size_t)sub * 16 + t];
            ushort4 ru = Rb4[(size_t)rel * 16 + t];
            acc.x += aj * (bf2f(hu.x) + bf2f(ru.x));
            acc.y += aj * (bf2f(hu.y) + bf2f(ru.y));
            acc.z += aj * (bf2f(hu.z) + bf2f(ru.z));
            acc.w += aj * (bf2f(hu.w) + bf2f(ru.w));
        }
    }
#pragma unroll
    for (int off = 16; off <= 32; off <<= 1) {
        acc.x += __shfl_xor(acc.x, off, 64);
        acc.y += __shfl_xor(acc.y, off, 64);
        acc.z += __shfl_xor(acc.z, off, 64);
        acc.w += __shfl_xor(acc.w, off, 64);
    }
    if (g == 0) out4[(size_t)node * 16 + t] = acc;
}

// in-place: io rows <- io rows @ Wh.T; rows streamed via wave-uniform float4 loads
__global__ void outgemm_inplace_kernel(const float* __restrict__ Wh, float* __restrict__ io,
                                       int n_node) {
    __shared__ float wT[64 * 64];   // wT[d*64+j] = Wh[j*64+d]
    int tid = threadIdx.x;
    for (int i = tid; i < 64 * 64; i += 256) {
        int j = i >> 6, d = i & 63;
        wT[d * 64 + j] = Wh[i];
    }
    __syncthreads();
    int wave = tid >> 6, j = tid & 63;
    int base = blockIdx.x * 32;              // 32 rows per block, 8 per wave
    for (int r = wave; r < 32; r += 4) {
        int row = base + r;
        if (row >= n_node) break;
        const float4* rp = (const float4*)(io + (size_t)row * 64);
        float acc = 0.f;
#pragma unroll
        for (int d4 = 0; d4 < 16; ++d4) {
            float4 m4 = rp[d4];              // wave-uniform broadcast load (L1)
            int d = d4 * 4;
            acc += m4.x * wT[(d + 0) * 64 + j] + m4.y * wT[(d + 1) * 64 + j]
                 + m4.z * wT[(d + 2) * 64 + j] + m4.w * wT[(d + 3) * 64 + j];
        }
        io[(size_t)row * 64 + j] = acc;      // same wave read the row fully first
    }
}

extern "C" void kernel_launch(void* const* d_in, const int* in_sizes, int n_in,
                              void* d_out, int out_size, void* d_ws, size_t ws_size,
                              hipStream_t stream) {
    const int*   q_rel     = (const int*)d_in[1];
    const float* hidden    = (const float*)d_in[2];
    const int*   edges     = (const int*)d_in[3];
    const float* rela      = (const float*)d_in[7];
    const float* Ws        = (const float*)d_in[8];
    const float* Wr        = (const float*)d_in[9];
    const float* Wqr       = (const float*)d_in[10];
    const float* bqr       = (const float*)d_in[11];
    const float* w_alpha_w = (const float*)d_in[12];
    const float* w_alpha_b = (const float*)d_in[13];
    const float* Wh        = (const float*)d_in[14];

    int n_node = in_sizes[2] / 64;
    int n_edge = in_sizes[3] / 6;
    int n_rel  = in_sizes[7] / 64;
    int batch  = in_sizes[1];

    int n_sblk = (n_node + SCAN_CHUNK - 1) / SCAN_CHUNK;   // scan blocks (<=1024)

    // workspace layout (~40 MB): Hb/Rlb overlay pk2 (pk2 dead after alpha_scatter)
    unsigned* Sb   = (unsigned*)d_ws;                     // n_node*16 uints (6.4 MB)
    unsigned* Rb   = Sb + (size_t)n_node * 16;            // n_rel*16
    unsigned* Qb   = Rb + (size_t)n_rel * 16;             // batch*16
    int*   counts  = (int*)(Qb + (size_t)batch * 16);     // n_node
    int*   offs    = counts + n_node;                     // n_node+1
    int*   cur     = offs + n_node + 1;                   // n_node
    int*   bsum    = cur + n_node;                        // n_sblk
    size_t rec_off = (size_t)(bsum + n_sblk - (int*)d_ws);
    rec_off = (rec_off + 3) & ~(size_t)3;                 // align 16B
    float2* rec    = (float2*)((int*)d_ws + rec_off);     // n_edge float2 (16 MB)
    int2*  pk2     = (int2*)(rec + n_edge);               // n_edge int2 (16 MB)
    ushort4* Hb4   = (ushort4*)pk2;                       // n_node*16 ushort4 (12.8 MB)
    ushort4* Rlb4  = Hb4 + (size_t)n_node * 16;           // n_rel*16 (51 KB) - fits in pk2

    (void)hipMemsetAsync(counts, 0, (size_t)n_node * sizeof(int), stream);

    proj32_bf16_kernel<<<(n_node + 7) / 8, 256, 0, stream>>>(hidden, Ws, Sb, n_node);
    proj32_bf16_kernel<<<(n_rel + 7) / 8, 256, 0, stream>>>(rela, Wr, Rb, n_rel);
    qproj_bf16_kernel<<<1, 256, 0, stream>>>(q_rel, rela, Wqr, bqr, Qb, batch);

    hist_pack_kernel<<<(n_edge + 255) / 256, 256, 0, stream>>>(edges, counts, pk2, n_edge);

    scan_partial_kernel<<<n_sblk, 256, 0, stream>>>(counts, bsum, n_node);
    scan_bsum_kernel<<<1, 1024, 0, stream>>>(bsum, offs, n_sblk, n_node);
    scan_final_kernel<<<n_sblk, 256, 0, stream>>>(counts, bsum, offs, cur, n_node);

    alpha_scatter_kernel<<<(n_edge + 15) / 16, 256, 0, stream>>>(
        pk2, Sb, Rb, Qb, (const float2*)w_alpha_w, w_alpha_b, cur, rec, n_edge);

    // convert gather tables to bf16 AFTER alpha_scatter (Hb4 overlays pk2)
    {
        int n4h = n_node * 16;   // hidden has n_node*64 floats = n4h float4s
        tobf16_kernel<<<(n4h + 255) / 256, 256, 0, stream>>>(
            (const float4*)hidden, Hb4, n4h);
        int n4r = n_rel * 16;
        tobf16_kernel<<<(n4r + 255) / 256, 256, 0, stream>>>(
            (const float4*)rela, Rlb4, n4r);
    }

    reduce_kernel<<<(n_node + 3) / 4, 256, 0, stream>>>(
        rec, offs, Hb4, Rlb4, (float4*)d_out, n_node);
    outgemm_inplace_kernel<<<(n_node + 31) / 32, 256, 0, stream>>>(Wh, (float*)d_out, n_node);
}